// Round 3
// baseline (389.489 us; speedup 1.0000x reference)
//
#include <hip/hip_runtime.h>

// Y_t = U^T * X_t * V  per token, via bf16 MFMA 16x16x32.
// v4: v3's token-loop pipeline at v2's occupancy.
//   - grid 1024 x TPB=2: exactly 4 blocks/CU resident (LDS 34816 -> 4/CU).
//   - single Tt buffer; two lgkm-only barriers per token (vmcnt prefetch
//     stays in flight across both).
//   - next-token x loads issued after stage-1 (fits 128 VGPR, 16 waves/CU).
//   - plain cached y stores (v3's nontemporal stores caused HBM RMW traffic).

typedef short bf16x8 __attribute__((ext_vector_type(8)));
typedef float f32x4  __attribute__((ext_vector_type(4)));

#define DIM   128
#define TP    136   // T^T LDS pitch (bf16): 272B rows, 16B-aligned, ~conflict-free
#define NTOK  2048
#define TPB   2     // tokens per block
#define GRID  (NTOK / TPB)

static __device__ __forceinline__ unsigned short f2bf(float f) {
    union { float f; unsigned u; } v; v.f = f;
    unsigned r = v.u + 0x7FFFu + ((v.u >> 16) & 1u);  // round-nearest-even
    return (unsigned short)(r >> 16);
}

// Build U/V bf16 fragment-swizzled copies in workspace (unchanged).
// Granule g in [0,2048) per matrix: g = (tile*4 + kk)*64 + lane.
// Granule holds 8 bf16: B[k][n] = src[k*128 + n] for n = tile*16 + (lane&15),
// k = kk*32 + (lane>>4)*8 + j, j=0..7. (For U this yields A[m=j1][k=i1] = U[i1*128+j1].)
__global__ void kron_prep_uv(const float* __restrict__ U,
                             const float* __restrict__ V,
                             unsigned short* __restrict__ swz) {
    int g = blockIdx.x * blockDim.x + threadIdx.x;   // 0..4095
    const float* src = (g < 2048) ? V : U;
    int gg   = g & 2047;
    int lane = gg & 63;
    int blk  = gg >> 6;
    int kk   = blk & 3;
    int tile = blk >> 2;
    int n  = tile * 16 + (lane & 15);
    int k0 = kk * 32 + (lane >> 4) * 8;
    bf16x8 v;
#pragma unroll
    for (int j = 0; j < 8; ++j)
        v[j] = (short)f2bf(src[(k0 + j) * DIM + n]);
    *(bf16x8*)(swz + (size_t)g * 8) = v;
}

__global__ __launch_bounds__(256, 4)
void kron_main(const float* __restrict__ x,
               const unsigned short* __restrict__ Vs,   // swizzled V (stage-1 B frags)
               const unsigned short* __restrict__ Us,   // swizzled U^T (stage-2 A frags)
               float* __restrict__ y) {
    __shared__ unsigned short Tt[DIM * TP];   // 34816 B single buffer -> 4 blocks/CU

    const int tid   = threadIdx.x;
    const int lane  = tid & 63;
    const int wave  = tid >> 6;     // owns X rows / Y rows [32*wave, 32*wave+32)
    const int m16   = lane & 15;
    const int q     = lane >> 4;
    const int tbase = blockIdx.x * TPB;

    // ---- hoist U^T fragments (reused every token) ----
    bf16x8 ua[2][4];
#pragma unroll
    for (int mt = 0; mt < 2; ++mt)
#pragma unroll
        for (int kk = 0; kk < 4; ++kk)
            ua[mt][kk] = *(const bf16x8*)(Us + (size_t)(((wave * 2 + mt) * 4 + kk) * 64 + lane) * 8);

    // ---- prologue: issue x loads for token 0 ----
    float4 raw[16];
    {
        const float* xp = x + (size_t)tbase * (DIM * DIM);
#pragma unroll
        for (int mt = 0; mt < 2; ++mt) {
            const float* rp = xp + (wave * 32 + mt * 16 + m16) * DIM + q * 8;
#pragma unroll
            for (int kk = 0; kk < 4; ++kk) {
                raw[(mt * 4 + kk) * 2 + 0] = *(const float4*)(rp + kk * 32);
                raw[(mt * 4 + kk) * 2 + 1] = *(const float4*)(rp + kk * 32 + 4);
            }
        }
    }

    for (int it = 0; it < TPB; ++it) {
        // ---- convert prefetched fp32 -> bf16 A-fragments ----
        bf16x8 af[2][4];
#pragma unroll
        for (int mt = 0; mt < 2; ++mt)
#pragma unroll
            for (int kk = 0; kk < 4; ++kk) {
                const float4 a = raw[(mt * 4 + kk) * 2 + 0];
                const float4 b = raw[(mt * 4 + kk) * 2 + 1];
                bf16x8 v;
                v[0] = (short)f2bf(a.x); v[1] = (short)f2bf(a.y);
                v[2] = (short)f2bf(a.z); v[3] = (short)f2bf(a.w);
                v[4] = (short)f2bf(b.x); v[5] = (short)f2bf(b.y);
                v[6] = (short)f2bf(b.z); v[7] = (short)f2bf(b.w);
                af[mt][kk] = v;
            }

        // ---- stage 1: T[32w..][:] = X_rows @ V ----
        f32x4 acc[2][8] = {};
#pragma unroll
        for (int kk = 0; kk < 4; ++kk)
#pragma unroll
            for (int nt = 0; nt < 8; ++nt) {
                const bf16x8 bv = *(const bf16x8*)(Vs + (size_t)((nt * 4 + kk) * 64 + lane) * 8);
#pragma unroll
                for (int mt = 0; mt < 2; ++mt)
                    acc[mt][nt] = __builtin_amdgcn_mfma_f32_16x16x32_bf16(af[mt][kk], bv, acc[mt][nt], 0, 0, 0);
            }

        // ---- issue next token's x loads (in flight across barriers + stage 2) ----
        if (it + 1 < TPB) {
            const float* xp = x + (size_t)(tbase + it + 1) * (DIM * DIM);
#pragma unroll
            for (int mt = 0; mt < 2; ++mt) {
                const float* rp = xp + (wave * 32 + mt * 16 + m16) * DIM + q * 8;
#pragma unroll
                for (int kk = 0; kk < 4; ++kk) {
                    raw[(mt * 4 + kk) * 2 + 0] = *(const float4*)(rp + kk * 32);
                    raw[(mt * 4 + kk) * 2 + 1] = *(const float4*)(rp + kk * 32 + 4);
                }
            }
        }

        // ---- write own T^T slice (bf16): Tt[j2][i1] ----
#pragma unroll
        for (int mt = 0; mt < 2; ++mt)
#pragma unroll
            for (int nt = 0; nt < 8; ++nt) {
                const int j2 = nt * 16 + m16;
                const int i1 = wave * 32 + mt * 16 + q * 4;
                unsigned p0 = (unsigned)f2bf(acc[mt][nt][0]) | ((unsigned)f2bf(acc[mt][nt][1]) << 16);
                unsigned p1 = (unsigned)f2bf(acc[mt][nt][2]) | ((unsigned)f2bf(acc[mt][nt][3]) << 16);
                uint2 w; w.x = p0; w.y = p1;
                *(uint2*)&Tt[j2 * TP + i1] = w;
            }

        // ---- barrier WITHOUT vmcnt drain: LDS writes visible, x prefetch live ----
        asm volatile("s_waitcnt lgkmcnt(0)" ::: "memory");
        __builtin_amdgcn_s_barrier();
        __builtin_amdgcn_sched_barrier(0);

        // ---- stage 2: Y[32w..][:] = U^T_rows @ T (reuse acc registers) ----
#pragma unroll
        for (int mt = 0; mt < 2; ++mt)
#pragma unroll
            for (int nt = 0; nt < 8; ++nt)
                acc[mt][nt] = (f32x4){0.f, 0.f, 0.f, 0.f};
#pragma unroll
        for (int kk = 0; kk < 4; ++kk)
#pragma unroll
            for (int nt = 0; nt < 8; ++nt) {
                const bf16x8 tb = *(const bf16x8*)&Tt[(nt * 16 + m16) * TP + kk * 32 + q * 8];
#pragma unroll
                for (int mt = 0; mt < 2; ++mt)
                    acc[mt][nt] = __builtin_amdgcn_mfma_f32_16x16x32_bf16(ua[mt][kk], tb, acc[mt][nt], 0, 0, 0);
            }

        // ---- store Y (fp32, plain cached stores) ----
        float* yp = y + (size_t)(tbase + it) * (DIM * DIM);
#pragma unroll
        for (int mt = 0; mt < 2; ++mt)
#pragma unroll
            for (int r = 0; r < 4; ++r) {
                const int row = wave * 32 + mt * 16 + q * 4 + r;
#pragma unroll
                for (int nt = 0; nt < 8; ++nt)
                    yp[row * DIM + nt * 16 + m16] = acc[mt][nt][r];
            }

        // ---- single-buffer reuse: all waves done reading Tt before next token ----
        if (it + 1 < TPB) {
            asm volatile("s_waitcnt lgkmcnt(0)" ::: "memory");
            __builtin_amdgcn_s_barrier();
            __builtin_amdgcn_sched_barrier(0);
        }
    }
}

extern "C" void kernel_launch(void* const* d_in, const int* in_sizes, int n_in,
                              void* d_out, int out_size, void* d_ws, size_t ws_size,
                              hipStream_t stream) {
    const float* x = (const float*)d_in[0];
    const float* U = (const float*)d_in[1];
    const float* V = (const float*)d_in[2];
    float*       y = (float*)d_out;

    unsigned short* swz = (unsigned short*)d_ws;   // [0,16384): V frags; [16384,32768): U frags
    kron_prep_uv<<<16, 256, 0, stream>>>(U, V, swz);
    kron_main<<<GRID, 256, 0, stream>>>(x, swz, swz + 2048 * 8, y);
}

// Round 4
// 251.076 us; speedup vs baseline: 1.5513x; 1.5513x over previous
//
#include <hip/hip_runtime.h>

// Y_t = U^T * X_t * V  per token, via bf16 MFMA 16x16x32.
// v5: 8-wave blocks for memory duty cycle.
//   - 512 threads/block, wave w owns 16 rows; one token per block, grid 2048.
//   - Same 34816 B LDS exchange (T^T), but 24-32 waves/CU (vs ~12 in v2):
//     more staggered x-load bursts per CU -> higher HBM duty cycle.
//   - NO cross-token register prefetch (v4's launch_bounds+raw[16] combo
//     spilled to scratch: WRITE_SIZE 131->438 MB). Per-wave state halved
//     instead: acc[8]=32 VGPR, x-prefetch 8xfloat4=32 VGPR.
//   - launch_bounds(512,6): VGPR cap ~85 (headroom, no forced spill).

typedef short bf16x8 __attribute__((ext_vector_type(8)));
typedef float f32x4  __attribute__((ext_vector_type(4)));

#define DIM   128
#define TP    136   // T^T LDS pitch (bf16): 272B rows, 16B-aligned, ~2-way banks
#define NTOK  2048

static __device__ __forceinline__ unsigned short f2bf(float f) {
    union { float f; unsigned u; } v; v.f = f;
    unsigned r = v.u + 0x7FFFu + ((v.u >> 16) & 1u);  // round-nearest-even
    return (unsigned short)(r >> 16);
}

// Build U/V bf16 fragment-swizzled copies in workspace (unchanged).
// Granule g in [0,2048) per matrix: g = (tile*4 + kk)*64 + lane.
// Granule holds 8 bf16: B[k][n] = src[k*128 + n] for n = tile*16 + (lane&15),
// k = kk*32 + (lane>>4)*8 + j, j=0..7. (For U this yields A[m=j1][k=i1] = U[i1*128+j1].)
__global__ void kron_prep_uv(const float* __restrict__ U,
                             const float* __restrict__ V,
                             unsigned short* __restrict__ swz) {
    int g = blockIdx.x * blockDim.x + threadIdx.x;   // 0..4095
    const float* src = (g < 2048) ? V : U;
    int gg   = g & 2047;
    int lane = gg & 63;
    int blk  = gg >> 6;
    int kk   = blk & 3;
    int tile = blk >> 2;
    int n  = tile * 16 + (lane & 15);
    int k0 = kk * 32 + (lane >> 4) * 8;
    bf16x8 v;
#pragma unroll
    for (int j = 0; j < 8; ++j)
        v[j] = (short)f2bf(src[(k0 + j) * DIM + n]);
    *(bf16x8*)(swz + (size_t)g * 8) = v;
}

__global__ __launch_bounds__(512, 6)
void kron_main(const float* __restrict__ x,
               const unsigned short* __restrict__ Vs,   // swizzled V (stage-1 B frags)
               const unsigned short* __restrict__ Us,   // swizzled U^T (stage-2 A frags)
               float* __restrict__ y) {
    __shared__ unsigned short Tt[DIM * TP];   // 34816 B

    const int tid  = threadIdx.x;
    const int lane = tid & 63;
    const int wave = tid >> 6;       // 0..7: owns X rows / Y rows [16*wave, 16*wave+16)
    const int m16  = lane & 15;
    const int q    = lane >> 4;
    const int r0   = wave * 16;
    const int t    = blockIdx.x;

    const float* xp = x + (size_t)t * (DIM * DIM);
    const float* rp = xp + (r0 + m16) * DIM + q * 8;

    // ---- issue all 8 x-row float4 loads (32 VGPR in flight) ----
    float4 xa[4], xb[4];
#pragma unroll
    for (int kk = 0; kk < 4; ++kk) {
        xa[kk] = *(const float4*)(rp + kk * 32);
        xb[kk] = *(const float4*)(rp + kk * 32 + 4);
    }

    // ---- stage 1: T[r0..r0+16)[:] = X_rows @ V ----
    f32x4 acc[8] = {};
#pragma unroll
    for (int kk = 0; kk < 4; ++kk) {
        bf16x8 af;
        af[0] = (short)f2bf(xa[kk].x); af[1] = (short)f2bf(xa[kk].y);
        af[2] = (short)f2bf(xa[kk].z); af[3] = (short)f2bf(xa[kk].w);
        af[4] = (short)f2bf(xb[kk].x); af[5] = (short)f2bf(xb[kk].y);
        af[6] = (short)f2bf(xb[kk].z); af[7] = (short)f2bf(xb[kk].w);
#pragma unroll
        for (int nt = 0; nt < 8; ++nt) {
            const bf16x8 bv = *(const bf16x8*)(Vs + (size_t)((nt * 4 + kk) * 64 + lane) * 8);
            acc[nt] = __builtin_amdgcn_mfma_f32_16x16x32_bf16(af, bv, acc[nt], 0, 0, 0);
        }
    }

    // ---- write own T^T slice (bf16): Tt[j2][i1], i1 in [r0, r0+16) ----
    // C layout: j2 = nt*16 + m16, i1 = r0 + q*4 + r -> 4 contiguous bf16 (uint2).
#pragma unroll
    for (int nt = 0; nt < 8; ++nt) {
        const int j2 = nt * 16 + m16;
        const int i1 = r0 + q * 4;
        unsigned p0 = (unsigned)f2bf(acc[nt][0]) | ((unsigned)f2bf(acc[nt][1]) << 16);
        unsigned p1 = (unsigned)f2bf(acc[nt][2]) | ((unsigned)f2bf(acc[nt][3]) << 16);
        uint2 w; w.x = p0; w.y = p1;
        *(uint2*)&Tt[j2 * TP + i1] = w;
    }

    // ---- barrier: LDS writes visible (lgkm only; no vmcnt dependency here) ----
    asm volatile("s_waitcnt lgkmcnt(0)" ::: "memory");
    __builtin_amdgcn_s_barrier();
    __builtin_amdgcn_sched_barrier(0);

    // ---- stage 2: Y[r0..r0+16)[:] = U^T_rows @ T ----
    f32x4 acc2[8] = {};
#pragma unroll
    for (int kk = 0; kk < 4; ++kk) {
        const bf16x8 ua = *(const bf16x8*)(Us + (size_t)((wave * 4 + kk) * 64 + lane) * 8);
#pragma unroll
        for (int nt = 0; nt < 8; ++nt) {
            const bf16x8 tb = *(const bf16x8*)&Tt[(nt * 16 + m16) * TP + kk * 32 + q * 8];
            acc2[nt] = __builtin_amdgcn_mfma_f32_16x16x32_bf16(ua, tb, acc2[nt], 0, 0, 0);
        }
    }

    // ---- store Y (fp32): j1 = r0 + q*4 + r, j2 = nt*16 + m16 ----
    float* yp = y + (size_t)t * (DIM * DIM);
#pragma unroll
    for (int r = 0; r < 4; ++r) {
        const int row = r0 + q * 4 + r;
#pragma unroll
        for (int nt = 0; nt < 8; ++nt)
            yp[row * DIM + nt * 16 + m16] = acc2[nt][r];
    }
}

extern "C" void kernel_launch(void* const* d_in, const int* in_sizes, int n_in,
                              void* d_out, int out_size, void* d_ws, size_t ws_size,
                              hipStream_t stream) {
    const float* x = (const float*)d_in[0];
    const float* U = (const float*)d_in[1];
    const float* V = (const float*)d_in[2];
    float*       y = (float*)d_out;

    unsigned short* swz = (unsigned short*)d_ws;   // [0,16384): V frags; [16384,32768): U frags
    kron_prep_uv<<<16, 256, 0, stream>>>(U, V, swz);
    kron_main<<<NTOK, 512, 0, stream>>>(x, swz, swz + 2048 * 8, y);
}